// Round 3
// baseline (41.797 us; speedup 1.0000x reference)
//
#include <hip/hip_runtime.h>
#include <hip/hip_bf16.h>
#include <math.h>

#define D_IN  128
#define NH    8
#define F_OUT 32
#define HID   256
#define D_EMB 64
#define BINS  200
#define FDIM  (HID + 2 * F_OUT + D_EMB)   // 384
#define CAP   128        // max matched edges (expected ~32; 4x margin)
#define PRE_BLOCKS 11    // precompute task blocks fused into the scan kernel

// ---------------- ws layout ----------------
// int  [0]                 count
// int  [16..16+CAP)        m_src ; +CAP m_trg ; +2CAP m_bin
// float base 512:
//   vsrc   [NH*D_IN]   a_src folded into Wproj rows
//   escall [BINS*NH]   dist-bin scores for every bin
//   strg   [16]        s_trg for li/ld
//   sms    [8]         Wms@ms
//   skipb  [512]       Wskip@nf[li/ld]  (t*256+r)
//   pre1   [256]       W1[:,0:256]@ms + W1[:,320:384]@demb_h + b1

__device__ __forceinline__ float red32(float v) {
#pragma unroll
  for (int o = 16; o > 0; o >>= 1) v += __shfl_down(v, o, 32);
  return v;
}

__global__ __launch_bounds__(256) void scan_pre(
    const int* __restrict__ trg, const int* __restrict__ src,
    const int* __restrict__ bins, const int* __restrict__ li_p,
    const int* __restrict__ ld_p, const int* __restrict__ dist_p, int nE,
    const float* __restrict__ nf, const float* __restrict__ ms,
    const float* __restrict__ Wproj, const float* __restrict__ a_src,
    const float* __restrict__ a_trg, const float* __restrict__ Wms,
    const float* __restrict__ demb_g, const float* __restrict__ Wdist,
    const float* __restrict__ Wskip,
    const float* __restrict__ W1, const float* __restrict__ b1,
    const float* __restrict__ demb_h,
    int* __restrict__ count, int* __restrict__ m_src,
    int* __restrict__ m_trg, int* __restrict__ m_bin,
    float* __restrict__ vsrc, float* __restrict__ escall,
    float* __restrict__ strg, float* __restrict__ sms,
    float* __restrict__ skipb, float* __restrict__ pre1) {
  const int b = blockIdx.x;
  const int tid = threadIdx.x;

  if (b < PRE_BLOCKS) {
    __shared__ __align__(16) float s_nf[D_IN];
    const int task = b;
    if (task < 4) {  // strg (0,1) ; skip rows (2,3)
      const int t = task & 1;
      const int node = t ? ld_p[0] : li_p[0];
      if (tid < 32) ((float4*)s_nf)[tid] = ((const float4*)nf)[(size_t)node * 32 + tid];
      __syncthreads();
      const float4* w4 = (const float4*)((task < 2 ? Wproj : Wskip) + tid * D_IN);
      const float4* x4 = (const float4*)s_nf;
      float acc = 0.f;
#pragma unroll
      for (int i = 0; i < 32; ++i) {
        float4 w = w4[i], x = x4[i];
        acc = fmaf(w.x, x.x, acc); acc = fmaf(w.y, x.y, acc);
        acc = fmaf(w.z, x.z, acc); acc = fmaf(w.w, x.w, acc);
      }
      if (task < 2) {
        int h = tid >> 5, f = tid & 31;
        float v = red32(acc * a_trg[h * F_OUT + f]);
        if (f == 0) strg[t * NH + h] = v;
      } else {
        skipb[t * 256 + tid] = acc;
      }
    } else if (task == 4) {  // sms[h] = Wms[h] . ms
      int h = tid >> 5, j = tid & 31;
      float v = 0.f;
      for (int k = j; k < HID; k += 32) v = fmaf(Wms[h * HID + k], ms[k], v);
      v = red32(v);
      if (j == 0) sms[h] = v;
    } else if (task < 9) {  // pre1 rows, 64 rows/task, 4 threads/row
      const int dist = dist_p[0];
      const int row = (task - 5) * 64 + (tid >> 2);
      const int l = tid & 3;
      const float* w = W1 + row * FDIM;
      float acc = 0.f;
      const float4* wm = (const float4*)(w + l * 64);
      const float4* mv = (const float4*)(ms + l * 64);
#pragma unroll
      for (int i = 0; i < 16; ++i) {
        float4 a = wm[i], x = mv[i];
        acc = fmaf(a.x, x.x, acc); acc = fmaf(a.y, x.y, acc);
        acc = fmaf(a.z, x.z, acc); acc = fmaf(a.w, x.w, acc);
      }
      const float* wd = w + HID + 2 * F_OUT + l * 16;
      const float* dv = demb_h + (size_t)dist * D_EMB + l * 16;
#pragma unroll
      for (int i = 0; i < 16; ++i) acc = fmaf(wd[i], dv[i], acc);
#pragma unroll
      for (int o = 2; o > 0; o >>= 1) acc += __shfl_down(acc, o, 4);
      if (l == 0) pre1[row] = acc + b1[row];
    } else if (task == 9) {  // vsrc[h,d] = sum_f a_src[h,f]*Wproj[h*32+f, d]
      const int d = tid & 127;
      const int hb = tid >> 7;
      for (int h4 = 0; h4 < 4; ++h4) {
        const int h = hb + h4 * 2;
        float acc = 0.f;
        for (int f = 0; f < F_OUT; ++f)
          acc = fmaf(a_src[h * F_OUT + f], Wproj[(h * F_OUT + f) * D_IN + d], acc);
        vsrc[h * D_IN + d] = acc;
      }
    } else {  // task 10: escall[bin,h] = demb_g[bin] . Wdist[h]
      if (tid < BINS) {
        const float* de = demb_g + tid * D_EMB;
        for (int h = 0; h < NH; ++h) {
          float acc = 0.f;
          const float* wd = Wdist + h * D_EMB;
          for (int d = 0; d < D_EMB; ++d) acc = fmaf(de[d], wd[d], acc);
          escall[tid * NH + h] = acc;
        }
      }
    }
    return;
  }

  // ---- edge scan ----
  const int li = li_p[0], ld = ld_p[0];
  const int gid = (b - PRE_BLOCKS) * 256 + tid;
  const int stride = (gridDim.x - PRE_BLOCKS) * 256;
  const int nE4 = nE >> 2;
  const int4* t4 = (const int4*)trg;
  for (int e4 = gid; e4 < nE4; e4 += stride) {
    int4 t = t4[e4];
    int ev[4] = {t.x, t.y, t.z, t.w};
#pragma unroll
    for (int k = 0; k < 4; ++k) {
      int tv = ev[k];
      if (tv == li || tv == ld) {
        int e = e4 * 4 + k;
        int pos = atomicAdd(count, 1);
        if (pos < CAP) { m_src[pos] = src[e]; m_trg[pos] = tv; m_bin[pos] = bins[e]; }
      }
    }
  }
  if (gid == 0) {
    for (int e = nE4 * 4; e < nE; ++e) {
      int tv = trg[e];
      if (tv == li || tv == ld) {
        int pos = atomicAdd(count, 1);
        if (pos < CAP) { m_src[pos] = src[e]; m_trg[pos] = tv; m_bin[pos] = bins[e]; }
      }
    }
  }
}

__global__ __launch_bounds__(256) void final_k(
    const float* __restrict__ nf,
    const int* __restrict__ li_p, const int* __restrict__ ld_p,
    const int* __restrict__ count, const int* __restrict__ m_src,
    const int* __restrict__ m_trg, const int* __restrict__ m_bin,
    const float* __restrict__ vsrc, const float* __restrict__ escall,
    const float* __restrict__ strg, const float* __restrict__ sms,
    const float* __restrict__ skipb, const float* __restrict__ pre1,
    const float* __restrict__ gbias, const float* __restrict__ Wproj,
    const float* __restrict__ W1, const float* __restrict__ W2,
    const float* __restrict__ b2, float* __restrict__ out) {
  __shared__ int   s_src[CAP];
  __shared__ int   s_tb[CAP];     // 0 if trg==li else 1
  __shared__ int   s_bin[CAP];
  __shared__ float s_p[CAP * NH];
  __shared__ float s_den[16];
  __shared__ __align__(16) float s_agg[2 * NH * D_IN];  // 8KB
  __shared__ float s_out[2 * 256];
  __shared__ __align__(16) float s_emb[2 * F_OUT];
  __shared__ float s_red[4];
  const int tid = threadIdx.x;
  const int li = li_p[0], ld = ld_p[0];
  int cnt = *count; if (cnt > CAP) cnt = CAP;

  // prefetch W1 column slice (independent of everything; completes behind scores)
  float4 w1r[16];
  const float4* w1p = (const float4*)(W1 + tid * FDIM + HID);
#pragma unroll
  for (int i = 0; i < 16; ++i) w1r[i] = w1p[i];

  if (tid < cnt) {
    int sv = m_src[tid];
    s_src[tid] = sv;
    s_tb[tid]  = (m_trg[tid] == li) ? 0 : 1;
    s_bin[tid] = m_bin[tid];
  }
  __syncthreads();

  // scores: exp(leaky_relu(ssrc + strg + sms + esc)); global max cancels in ratio
  for (int idx = tid; idx < cnt * NH; idx += 256) {
    int e = idx >> 3, h = idx & 7;
    const float4* nfr = (const float4*)(nf + (size_t)s_src[e] * D_IN);
    const float4* vs = (const float4*)(vsrc + h * D_IN);
    float acc = 0.f;
#pragma unroll
    for (int i = 0; i < 32; ++i) {
      float4 a = nfr[i], v = vs[i];
      acc = fmaf(a.x, v.x, acc); acc = fmaf(a.y, v.y, acc);
      acc = fmaf(a.z, v.z, acc); acc = fmaf(a.w, v.w, acc);
    }
    int t = s_tb[e];
    float sc = acc + strg[t * NH + h] + sms[h] + escall[s_bin[e] * NH + h];
    sc = sc > 0.f ? sc : 0.2f * sc;
    s_p[idx] = expf(sc);
  }
  __syncthreads();

  if (tid < 16) {
    int t = tid >> 3, h = tid & 7;
    float d = 0.f;
    for (int e = 0; e < cnt; ++e) if (s_tb[e] == t) d += s_p[e * NH + h];
    s_den[tid] = d + 1e-16f;
  }
  __syncthreads();

  // agg[t,h,d] = (sum_e attn * nf[src_e,d]) ; nf rows L1-warm from score phase
  {
    const int t = tid >> 7, h = (tid >> 4) & 7, d0 = (tid & 15) * 8;
    float acc[8] = {0.f};
    for (int e = 0; e < cnt; ++e) {
      if (s_tb[e] == t) {
        float w = s_p[e * NH + h];
        const float4* nfr = (const float4*)(nf + (size_t)s_src[e] * D_IN + d0);
        float4 a0 = nfr[0], a1 = nfr[1];
        acc[0] = fmaf(w, a0.x, acc[0]); acc[1] = fmaf(w, a0.y, acc[1]);
        acc[2] = fmaf(w, a0.z, acc[2]); acc[3] = fmaf(w, a0.w, acc[3]);
        acc[4] = fmaf(w, a1.x, acc[4]); acc[5] = fmaf(w, a1.y, acc[5]);
        acc[6] = fmaf(w, a1.z, acc[6]); acc[7] = fmaf(w, a1.w, acc[7]);
      }
    }
    float inv = 1.0f / s_den[t * NH + h];
#pragma unroll
    for (int j = 0; j < 8; ++j) s_agg[t * NH * D_IN + h * D_IN + d0 + j] = acc[j] * inv;
  }
  __syncthreads();

  // out[t,r] = agg[t,h] . Wproj[r] + skip[t,r]   (r = h*32+f = tid)
  {
    const int h = tid >> 5;
    float acc0 = skipb[tid], acc1 = skipb[256 + tid];
    const float4* w4 = (const float4*)(Wproj + tid * D_IN);
    const float4* g0 = (const float4*)(s_agg + h * D_IN);
    const float4* g1 = (const float4*)(s_agg + NH * D_IN + h * D_IN);
#pragma unroll
    for (int i = 0; i < 32; ++i) {
      float4 w = w4[i], a = g0[i], b = g1[i];
      acc0 = fmaf(w.x, a.x, acc0); acc0 = fmaf(w.y, a.y, acc0);
      acc0 = fmaf(w.z, a.z, acc0); acc0 = fmaf(w.w, a.w, acc0);
      acc1 = fmaf(w.x, b.x, acc1); acc1 = fmaf(w.y, b.y, acc1);
      acc1 = fmaf(w.z, b.z, acc1); acc1 = fmaf(w.w, b.w, acc1);
    }
    s_out[tid] = acc0; s_out[256 + tid] = acc1;
  }
  __syncthreads();

  if (tid < 2 * F_OUT) {  // head-mean + bias + ELU
    int t = tid >> 5, f = tid & 31;
    float s = 0.f;
#pragma unroll
    for (int h = 0; h < NH; ++h) s += s_out[t * 256 + h * F_OUT + f];
    s = s * 0.125f + gbias[f];
    s_emb[tid] = s > 0.f ? s : expm1f(s);
  }
  __syncthreads();

  // h1 = relu(pre1 + W1[:,256:320] @ emb); out = W2 . h1 + b2
  float acc = pre1[tid];
  const float4* e4 = (const float4*)s_emb;
#pragma unroll
  for (int i = 0; i < 16; ++i) {
    float4 w = w1r[i], x = e4[i];
    acc = fmaf(w.x, x.x, acc); acc = fmaf(w.y, x.y, acc);
    acc = fmaf(w.z, x.z, acc); acc = fmaf(w.w, x.w, acc);
  }
  acc = fmaxf(acc, 0.f);
  float c = W2[tid] * acc;
#pragma unroll
  for (int o = 32; o > 0; o >>= 1) c += __shfl_down(c, o, 64);
  if ((tid & 63) == 0) s_red[tid >> 6] = c;
  __syncthreads();
  if (tid == 0) out[0] = s_red[0] + s_red[1] + s_red[2] + s_red[3] + b2[0];
}

extern "C" void kernel_launch(void* const* d_in, const int* in_sizes, int n_in,
                              void* d_out, int out_size, void* d_ws, size_t ws_size,
                              hipStream_t stream) {
  const float* nf     = (const float*)d_in[0];
  const int*   esrc   = (const int*)d_in[1];
  const int*   etrg   = (const int*)d_in[2];
  const int*   ebin   = (const int*)d_in[3];
  const float* ms     = (const float*)d_in[4];
  const int*   li_p   = (const int*)d_in[5];
  const int*   ld_p   = (const int*)d_in[6];
  const int*   dist_p = (const int*)d_in[7];
  const float* Wproj  = (const float*)d_in[8];
  const float* a_src  = (const float*)d_in[9];
  const float* a_trg  = (const float*)d_in[10];
  const float* Wms    = (const float*)d_in[11];
  const float* demb_g = (const float*)d_in[12];
  const float* Wdist  = (const float*)d_in[13];
  const float* Wskip  = (const float*)d_in[14];
  const float* gbias  = (const float*)d_in[15];
  const float* demb_h = (const float*)d_in[16];
  const float* W1     = (const float*)d_in[17];
  const float* b1     = (const float*)d_in[18];
  const float* W2     = (const float*)d_in[19];
  const float* b2     = (const float*)d_in[20];
  const int nE = in_sizes[1];

  int* ws_i  = (int*)d_ws;
  int*   count = ws_i;
  int*   m_src = ws_i + 16;
  int*   m_trg = m_src + CAP;
  int*   m_bin = m_trg + CAP;
  float* fb     = (float*)d_ws + 512;
  float* vsrc   = fb;                     // NH*D_IN = 1024
  float* escall = vsrc + NH * D_IN;       // BINS*NH = 1600
  float* strg   = escall + BINS * NH;     // 16
  float* sms    = strg + 16;              // 8
  float* skipb  = sms + 8;                // 512
  float* pre1   = skipb + 512;            // 256

  hipMemsetAsync(count, 0, sizeof(int), stream);

  int scan_blocks = (nE / 4 + 255) / 256;
  if (scan_blocks < 1) scan_blocks = 1;
  if (scan_blocks > 2048) scan_blocks = 2048;
  scan_pre<<<scan_blocks + PRE_BLOCKS, 256, 0, stream>>>(
      etrg, esrc, ebin, li_p, ld_p, dist_p, nE,
      nf, ms, Wproj, a_src, a_trg, Wms, demb_g, Wdist, Wskip, W1, b1, demb_h,
      count, m_src, m_trg, m_bin, vsrc, escall, strg, sms, skipb, pre1);

  final_k<<<1, 256, 0, stream>>>(nf, li_p, ld_p, count, m_src, m_trg, m_bin,
                                 vsrc, escall, strg, sms, skipb, pre1,
                                 gbias, Wproj, W1, W2, b2, (float*)d_out);
}

// Round 4
// 40.271 us; speedup vs baseline: 1.0379x; 1.0379x over previous
//
#include <hip/hip_runtime.h>
#include <hip/hip_bf16.h>
#include <math.h>

#define D_IN  128
#define NH    8
#define F_OUT 32
#define HID   256
#define D_EMB 64
#define BINS  200
#define FDIM  (HID + 2 * F_OUT + D_EMB)   // 384
#define CAP   128        // max matched edges tracked (expected ~32)
#define SNF   64         // edges whose nf rows are staged in LDS (P(cnt>64) ~ 1e-7)
#define PRE_BLOCKS 11

// ---------------- ws layout ----------------
// int  [0] count ; [16..16+CAP) m_src ; +CAP m_trg ; +2CAP m_bin
// float base 512:
//   vsrc[NH*D_IN] escall[BINS*NH] strg[16] sms[8] skipb[512] pre1[256]

__device__ __forceinline__ float red32(float v) {
#pragma unroll
  for (int o = 16; o > 0; o >>= 1) v += __shfl_down(v, o, 32);
  return v;
}

__global__ void zero_count(int* c) { if (threadIdx.x == 0) *c = 0; }

__global__ __launch_bounds__(256) void scan_pre(
    const int* __restrict__ trg, const int* __restrict__ src,
    const int* __restrict__ bins, const int* __restrict__ li_p,
    const int* __restrict__ ld_p, const int* __restrict__ dist_p, int nE,
    const float* __restrict__ nf, const float* __restrict__ ms,
    const float* __restrict__ Wproj, const float* __restrict__ a_src,
    const float* __restrict__ a_trg, const float* __restrict__ Wms,
    const float* __restrict__ demb_g, const float* __restrict__ Wdist,
    const float* __restrict__ Wskip,
    const float* __restrict__ W1, const float* __restrict__ b1,
    const float* __restrict__ demb_h,
    int* __restrict__ count, int* __restrict__ m_src,
    int* __restrict__ m_trg, int* __restrict__ m_bin,
    float* __restrict__ vsrc, float* __restrict__ escall,
    float* __restrict__ strg, float* __restrict__ sms,
    float* __restrict__ skipb, float* __restrict__ pre1) {
  const int b = blockIdx.x;
  const int tid = threadIdx.x;

  if (b < PRE_BLOCKS) {
    __shared__ __align__(16) float s_nf[D_IN];
    const int task = b;
    if (task < 4) {  // strg (0,1) ; skip rows (2,3)
      const int t = task & 1;
      const int node = t ? ld_p[0] : li_p[0];
      if (tid < 32) ((float4*)s_nf)[tid] = ((const float4*)nf)[(size_t)node * 32 + tid];
      __syncthreads();
      const float4* w4 = (const float4*)((task < 2 ? Wproj : Wskip) + tid * D_IN);
      const float4* x4 = (const float4*)s_nf;
      float acc = 0.f;
#pragma unroll
      for (int i = 0; i < 32; ++i) {
        float4 w = w4[i], x = x4[i];
        acc = fmaf(w.x, x.x, acc); acc = fmaf(w.y, x.y, acc);
        acc = fmaf(w.z, x.z, acc); acc = fmaf(w.w, x.w, acc);
      }
      if (task < 2) {
        int h = tid >> 5, f = tid & 31;
        float v = red32(acc * a_trg[h * F_OUT + f]);
        if (f == 0) strg[t * NH + h] = v;
      } else {
        skipb[t * 256 + tid] = acc;
      }
    } else if (task == 4) {  // sms[h] = Wms[h] . ms
      int h = tid >> 5, j = tid & 31;
      float v = 0.f;
      for (int k = j; k < HID; k += 32) v = fmaf(Wms[h * HID + k], ms[k], v);
      v = red32(v);
      if (j == 0) sms[h] = v;
    } else if (task < 9) {  // pre1 rows, 64 rows/task, 4 threads/row
      const int dist = dist_p[0];
      const int row = (task - 5) * 64 + (tid >> 2);
      const int l = tid & 3;
      const float* w = W1 + row * FDIM;
      float acc = 0.f;
      const float4* wm = (const float4*)(w + l * 64);
      const float4* mv = (const float4*)(ms + l * 64);
#pragma unroll
      for (int i = 0; i < 16; ++i) {
        float4 a = wm[i], x = mv[i];
        acc = fmaf(a.x, x.x, acc); acc = fmaf(a.y, x.y, acc);
        acc = fmaf(a.z, x.z, acc); acc = fmaf(a.w, x.w, acc);
      }
      const float* wd = w + HID + 2 * F_OUT + l * 16;
      const float* dv = demb_h + (size_t)dist * D_EMB + l * 16;
#pragma unroll
      for (int i = 0; i < 16; ++i) acc = fmaf(wd[i], dv[i], acc);
#pragma unroll
      for (int o = 2; o > 0; o >>= 1) acc += __shfl_down(acc, o, 4);
      if (l == 0) pre1[row] = acc + b1[row];
    } else if (task == 9) {  // vsrc[h,d] = sum_f a_src[h,f]*Wproj[h*32+f, d]
      const int d = tid & 127;
      const int hb = tid >> 7;
      for (int h4 = 0; h4 < 4; ++h4) {
        const int h = hb + h4 * 2;
        float acc = 0.f;
        for (int f = 0; f < F_OUT; ++f)
          acc = fmaf(a_src[h * F_OUT + f], Wproj[(h * F_OUT + f) * D_IN + d], acc);
        vsrc[h * D_IN + d] = acc;
      }
    } else {  // task 10: escall[bin,h] = demb_g[bin] . Wdist[h]
      if (tid < BINS) {
        const float* de = demb_g + tid * D_EMB;
        for (int h = 0; h < NH; ++h) {
          float acc = 0.f;
          const float* wd = Wdist + h * D_EMB;
          for (int d = 0; d < D_EMB; ++d) acc = fmaf(de[d], wd[d], acc);
          escall[tid * NH + h] = acc;
        }
      }
    }
    return;
  }

  // ---- edge scan ----
  const int li = li_p[0], ld = ld_p[0];
  const int gid = (b - PRE_BLOCKS) * 256 + tid;
  const int stride = (gridDim.x - PRE_BLOCKS) * 256;
  const int nE4 = nE >> 2;
  const int4* t4 = (const int4*)trg;
  for (int e4 = gid; e4 < nE4; e4 += stride) {
    int4 t = t4[e4];
    int ev[4] = {t.x, t.y, t.z, t.w};
#pragma unroll
    for (int k = 0; k < 4; ++k) {
      int tv = ev[k];
      if (tv == li || tv == ld) {
        int e = e4 * 4 + k;
        int pos = atomicAdd(count, 1);
        if (pos < CAP) { m_src[pos] = src[e]; m_trg[pos] = tv; m_bin[pos] = bins[e]; }
      }
    }
  }
  if (gid == 0) {
    for (int e = nE4 * 4; e < nE; ++e) {
      int tv = trg[e];
      if (tv == li || tv == ld) {
        int pos = atomicAdd(count, 1);
        if (pos < CAP) { m_src[pos] = src[e]; m_trg[pos] = tv; m_bin[pos] = bins[e]; }
      }
    }
  }
}

__global__ __launch_bounds__(512, 1) void final_k(
    const float* __restrict__ nf,
    const int* __restrict__ li_p, const int* __restrict__ ld_p,
    const int* __restrict__ count, const int* __restrict__ m_src,
    const int* __restrict__ m_trg, const int* __restrict__ m_bin,
    const float* __restrict__ vsrc, const float* __restrict__ escall,
    const float* __restrict__ strg, const float* __restrict__ sms,
    const float* __restrict__ skipb, const float* __restrict__ pre1,
    const float* __restrict__ gbias, const float* __restrict__ Wproj,
    const float* __restrict__ W1, const float* __restrict__ W2,
    const float* __restrict__ b2, float* __restrict__ out) {
  __shared__ int   s_src[CAP];
  __shared__ int   s_tb[CAP];
  __shared__ int   s_bin[CAP];
  __shared__ float s_p[CAP * NH];                   // 4 KB
  __shared__ float s_den[16];
  __shared__ __align__(16) float s_nf[SNF][D_IN];   // 32 KB
  __shared__ __align__(16) float s_vsrc[NH * D_IN]; // 4 KB
  __shared__ __align__(16) float s_esc[BINS * NH];  // 6.4 KB
  __shared__ __align__(16) float s_skip[512];
  __shared__ __align__(16) float s_pre1[HID];
  __shared__ __align__(16) float s_w2[HID];
  __shared__ float s_strg[16], s_sms[8];
  __shared__ __align__(16) float s_agg[2 * NH * D_IN]; // 8 KB
  __shared__ float s_out[2 * 256];
  __shared__ __align__(16) float s_emb[2 * F_OUT];
  __shared__ float s_red[8];

  const int tid = threadIdx.x;
  const int li = li_p[0], ld = ld_p[0];
  float b2v = 0.f;
  if (tid == 0) b2v = b2[0];

  // ---- phase 0: scan-independent prefetch (issued before the dependent chain) ----
  float4 wp[32];  // threads [0,256): full Wproj row `tid`
  float4 w1[16];  // threads [256,512): W1 row (tid-256), cols 256..320
  if (tid < 256) {
    const float4* p = (const float4*)(Wproj + tid * D_IN);
#pragma unroll
    for (int i = 0; i < 32; ++i) wp[i] = p[i];
  } else {
    const float4* p = (const float4*)(W1 + (size_t)(tid - 256) * FDIM + HID);
#pragma unroll
    for (int i = 0; i < 16; ++i) w1[i] = p[i];
  }
  if (tid < 256) ((float4*)s_vsrc)[tid] = ((const float4*)vsrc)[tid];
  if (tid < 400) ((float4*)s_esc)[tid]  = ((const float4*)escall)[tid];
  if (tid < 128) ((float4*)s_skip)[tid] = ((const float4*)skipb)[tid];
  if (tid < 64)  ((float4*)s_pre1)[tid] = ((const float4*)pre1)[tid];
  if (tid < 64)  ((float4*)s_w2)[tid]   = ((const float4*)W2)[tid];
  if (tid < 16)  s_strg[tid] = strg[tid];
  if (tid < 8)   s_sms[tid]  = sms[tid];

  // ---- phase 1: edge metadata + nf staging ----
  int cnt = *count; if (cnt > CAP) cnt = CAP;
  if (tid < cnt) {
    s_src[tid] = m_src[tid];
    s_tb[tid]  = (m_trg[tid] == li) ? 0 : 1;
    s_bin[tid] = m_bin[tid];
  }
  const int lim = cnt < SNF ? cnt : SNF;
  for (int e = tid >> 5; e < lim; e += 16) {   // 16 edges per round, 32 thr/edge
    int sv = m_src[e];
    ((float4*)s_nf[e])[tid & 31] =
        ((const float4*)(nf + (size_t)sv * D_IN))[tid & 31];
  }
  __syncthreads();

  // ---- phase 2: scores  exp(leaky_relu(.)) ; reference global max cancels ----
  for (int idx = tid; idx < cnt * NH; idx += 512) {
    int e = idx >> 3, h = idx & 7;
    const float4* vs = (const float4*)(s_vsrc + h * D_IN);
    float acc = 0.f;
    if (e < SNF) {
      const float4* xr = (const float4*)s_nf[e];
#pragma unroll
      for (int i = 0; i < 32; ++i) {
        float4 a = xr[i], v = vs[i];
        acc = fmaf(a.x, v.x, acc); acc = fmaf(a.y, v.y, acc);
        acc = fmaf(a.z, v.z, acc); acc = fmaf(a.w, v.w, acc);
      }
    } else {
      const float4* xr = (const float4*)(nf + (size_t)s_src[e] * D_IN);
#pragma unroll
      for (int i = 0; i < 32; ++i) {
        float4 a = xr[i], v = vs[i];
        acc = fmaf(a.x, v.x, acc); acc = fmaf(a.y, v.y, acc);
        acc = fmaf(a.z, v.z, acc); acc = fmaf(a.w, v.w, acc);
      }
    }
    int t = s_tb[e];
    float sc = acc + s_strg[t * NH + h] + s_sms[h] + s_esc[s_bin[e] * NH + h];
    sc = sc > 0.f ? sc : 0.2f * sc;
    s_p[idx] = expf(sc);
  }
  __syncthreads();

  // ---- phase 3: denominators ----
  if (tid < 16) {
    int t = tid >> 3, h = tid & 7;
    float d = 0.f;
    for (int e = 0; e < cnt; ++e) if (s_tb[e] == t) d += s_p[e * NH + h];
    s_den[tid] = d + 1e-16f;
  }
  __syncthreads();

  // ---- phase 4: agg[t,h,d] = sum_e attn * nf[src_e,d]  (LDS only) ----
  {
    const int h = tid >> 6, d0 = (tid & 63) * 2;
    float a00 = 0.f, a01 = 0.f, a10 = 0.f, a11 = 0.f;
    for (int e = 0; e < cnt; ++e) {
      float w = s_p[e * NH + h];
      float v0, v1;
      if (e < SNF) { v0 = s_nf[e][d0]; v1 = s_nf[e][d0 + 1]; }
      else {
        const float* g = nf + (size_t)s_src[e] * D_IN + d0;
        v0 = g[0]; v1 = g[1];
      }
      if (s_tb[e]) { a10 = fmaf(w, v0, a10); a11 = fmaf(w, v1, a11); }
      else         { a00 = fmaf(w, v0, a00); a01 = fmaf(w, v1, a01); }
    }
    float i0 = 1.0f / s_den[h], i1 = 1.0f / s_den[8 + h];
    s_agg[h * D_IN + d0]              = a00 * i0;
    s_agg[h * D_IN + d0 + 1]          = a01 * i0;
    s_agg[NH * D_IN + h * D_IN + d0]     = a10 * i1;
    s_agg[NH * D_IN + h * D_IN + d0 + 1] = a11 * i1;
  }
  __syncthreads();

  // ---- phase 5: out[t,r] = agg[t,h] . Wproj[r] + skip[t,r]  (regs x LDS) ----
  if (tid < 256) {
    const int h = tid >> 5;
    float acc0 = s_skip[tid], acc1 = s_skip[256 + tid];
    const float4* g0 = (const float4*)(s_agg + h * D_IN);
    const float4* g1 = (const float4*)(s_agg + NH * D_IN + h * D_IN);
#pragma unroll
    for (int i = 0; i < 32; ++i) {
      float4 w = wp[i], a = g0[i], b = g1[i];
      acc0 = fmaf(w.x, a.x, acc0); acc0 = fmaf(w.y, a.y, acc0);
      acc0 = fmaf(w.z, a.z, acc0); acc0 = fmaf(w.w, a.w, acc0);
      acc1 = fmaf(w.x, b.x, acc1); acc1 = fmaf(w.y, b.y, acc1);
      acc1 = fmaf(w.z, b.z, acc1); acc1 = fmaf(w.w, b.w, acc1);
    }
    s_out[tid] = acc0; s_out[256 + tid] = acc1;
  }
  __syncthreads();

  // ---- phase 6: head-mean + bias + ELU ----
  if (tid < 2 * F_OUT) {
    int t = tid >> 5, f = tid & 31;
    float s = 0.f;
#pragma unroll
    for (int h = 0; h < NH; ++h) s += s_out[t * 256 + h * F_OUT + f];
    s = s * 0.125f + gbias[f];
    s_emb[tid] = s > 0.f ? s : expm1f(s);
  }
  __syncthreads();

  // ---- phase 7: MLP  h1 = relu(pre1 + W1emb @ emb); out = W2.h1 + b2 ----
  float c = 0.f;
  if (tid >= 256) {
    const int row = tid - 256;
    float acc = s_pre1[row];
    const float4* e4 = (const float4*)s_emb;
#pragma unroll
    for (int i = 0; i < 16; ++i) {
      float4 w = w1[i], x = e4[i];
      acc = fmaf(w.x, x.x, acc); acc = fmaf(w.y, x.y, acc);
      acc = fmaf(w.z, x.z, acc); acc = fmaf(w.w, x.w, acc);
    }
    acc = fmaxf(acc, 0.f);
    c = s_w2[row] * acc;
  }
#pragma unroll
  for (int o = 32; o > 0; o >>= 1) c += __shfl_down(c, o, 64);
  if ((tid & 63) == 0) s_red[tid >> 6] = c;
  __syncthreads();
  if (tid == 0) {
    float s = 0.f;
#pragma unroll
    for (int w = 0; w < 8; ++w) s += s_red[w];
    out[0] = s + b2v;
  }
}

extern "C" void kernel_launch(void* const* d_in, const int* in_sizes, int n_in,
                              void* d_out, int out_size, void* d_ws, size_t ws_size,
                              hipStream_t stream) {
  const float* nf     = (const float*)d_in[0];
  const int*   esrc   = (const int*)d_in[1];
  const int*   etrg   = (const int*)d_in[2];
  const int*   ebin   = (const int*)d_in[3];
  const float* ms     = (const float*)d_in[4];
  const int*   li_p   = (const int*)d_in[5];
  const int*   ld_p   = (const int*)d_in[6];
  const int*   dist_p = (const int*)d_in[7];
  const float* Wproj  = (const float*)d_in[8];
  const float* a_src  = (const float*)d_in[9];
  const float* a_trg  = (const float*)d_in[10];
  const float* Wms    = (const float*)d_in[11];
  const float* demb_g = (const float*)d_in[12];
  const float* Wdist  = (const float*)d_in[13];
  const float* Wskip  = (const float*)d_in[14];
  const float* gbias  = (const float*)d_in[15];
  const float* demb_h = (const float*)d_in[16];
  const float* W1     = (const float*)d_in[17];
  const float* b1     = (const float*)d_in[18];
  const float* W2     = (const float*)d_in[19];
  const float* b2     = (const float*)d_in[20];
  const int nE = in_sizes[1];

  int* ws_i  = (int*)d_ws;
  int*   count = ws_i;
  int*   m_src = ws_i + 16;
  int*   m_trg = m_src + CAP;
  int*   m_bin = m_trg + CAP;
  float* fb     = (float*)d_ws + 512;
  float* vsrc   = fb;                     // NH*D_IN = 1024
  float* escall = vsrc + NH * D_IN;       // BINS*NH = 1600
  float* strg   = escall + BINS * NH;     // 16
  float* sms    = strg + 16;              // 8
  float* skipb  = sms + 8;                // 512
  float* pre1   = skipb + 512;            // 256

  zero_count<<<1, 64, 0, stream>>>(count);

  int scan_blocks = (nE / 4 + 255) / 256;
  if (scan_blocks < 1) scan_blocks = 1;
  if (scan_blocks > 2048) scan_blocks = 2048;
  scan_pre<<<scan_blocks + PRE_BLOCKS, 256, 0, stream>>>(
      etrg, esrc, ebin, li_p, ld_p, dist_p, nE,
      nf, ms, Wproj, a_src, a_trg, Wms, demb_g, Wdist, Wskip, W1, b1, demb_h,
      count, m_src, m_trg, m_bin, vsrc, escall, strg, sms, skipb, pre1);

  final_k<<<1, 512, 0, stream>>>(nf, li_p, ld_p, count, m_src, m_trg, m_bin,
                                 vsrc, escall, strg, sms, skipb, pre1,
                                 gbias, Wproj, W1, W2, b2, (float*)d_out);
}